// Round 1
// baseline (224.383 us; speedup 1.0000x reference)
//
#include <hip/hip_runtime.h>
#include <math.h>

#define DDIM 128

// v[t] = dot(W2 row t, w3[0:128]), t in [0,256)
__global__ void prep_v_kernel(const float* __restrict__ w2,
                              const float* __restrict__ w3,
                              float* __restrict__ v) {
    int t = threadIdx.x;  // 256 threads, one per row of W2
    const float4* row = (const float4*)(w2 + (size_t)t * DDIM);
    const float4* w3c = (const float4*)w3;
    float acc = 0.f;
#pragma unroll
    for (int c = 0; c < DDIM / 4; ++c) {
        float4 a = row[c];
        float4 b = w3c[c];
        acc += a.x * b.x + a.y * b.y + a.z * b.z + a.w * b.w;
    }
    v[t] = acc;
}

// One edge per 32-lane half-wave. Lane `sub` handles dims [4*sub, 4*sub+4).
__global__ void edge_score_kernel(const int* __restrict__ e_true,
                                  const int* __restrict__ e_false,
                                  const float* __restrict__ z,
                                  const float* __restrict__ w3,
                                  const float* __restrict__ v,
                                  float* __restrict__ out,
                                  int n_true, int n_total) {
    const int gtid    = blockIdx.x * blockDim.x + threadIdx.x;
    const int sub     = threadIdx.x & 31;
    const int group   = gtid >> 5;
    const int ngroups = (gridDim.x * blockDim.x) >> 5;

    // Per-lane invariant fragments (L1-resident after first touch).
    const float4 v1 = ((const float4*)v)[sub];            // v[4sub .. 4sub+3]
    const float4 v2 = ((const float4*)v)[32 + sub];       // v[128+4sub ..]
    const float4 wb = ((const float4*)(w3 + DDIM))[sub];  // w3[128+4sub ..]

    for (int e = group; e < n_total; e += ngroups) {
        int2 ep = (e < n_true) ? ((const int2*)e_true)[e]
                               : ((const int2*)e_false)[e - n_true];

        const float4 zi = ((const float4*)(z + (size_t)ep.x * DDIM))[sub];
        const float4 zj = ((const float4*)(z + (size_t)ep.y * DDIM))[sub];

        float p = fmaxf(zi.x, 0.f) * v1.x + fmaxf(zi.y, 0.f) * v1.y +
                  fmaxf(zi.z, 0.f) * v1.z + fmaxf(zi.w, 0.f) * v1.w +
                  fmaxf(zj.x, 0.f) * v2.x + fmaxf(zj.y, 0.f) * v2.y +
                  fmaxf(zj.z, 0.f) * v2.z + fmaxf(zj.w, 0.f) * v2.w +
                  zi.x * zj.x * wb.x + zi.y * zj.y * wb.y +
                  zi.z * zj.z * wb.z + zi.w * zj.w * wb.w;

        // Reduce across the 32-lane group.
#pragma unroll
        for (int off = 16; off; off >>= 1) p += __shfl_down(p, off, 32);

        if (sub == 0) out[e] = 1.f / (1.f + __expf(-p));
    }
}

extern "C" void kernel_launch(void* const* d_in, const int* in_sizes, int n_in,
                              void* d_out, int out_size, void* d_ws, size_t ws_size,
                              hipStream_t stream) {
    // inputs: 0=X(unused), 1=train_edges(int32, E_T*2), 2=train_false_edges(int32, E_F*2),
    //         3=z(f32, N*128), 4=weight_two(f32, 256*128), 5=weight_three(f32, 256)
    const int*   e_true  = (const int*)d_in[1];
    const int*   e_false = (const int*)d_in[2];
    const float* z       = (const float*)d_in[3];
    const float* w2      = (const float*)d_in[4];
    const float* w3      = (const float*)d_in[5];
    float*       out     = (float*)d_out;
    float*       v       = (float*)d_ws;  // 256 floats

    const int n_true  = in_sizes[1] / 2;
    const int n_total = out_size;

    prep_v_kernel<<<1, 256, 0, stream>>>(w2, w3, v);

    const int block  = 256;
    const int blocks = 4096;  // 32768 edge-groups, ~30 edges each via grid-stride
    edge_score_kernel<<<blocks, block, 0, stream>>>(e_true, e_false, z, w3, v,
                                                    out, n_true, n_total);
}

// Round 2
// 168.191 us; speedup vs baseline: 1.3341x; 1.3341x over previous
//
#include <hip/hip_runtime.h>
#include <math.h>

#define DDIM 128

typedef _Float16 v2h __attribute__((ext_vector_type(2)));

__device__ __forceinline__ float dot2acc(v2h a, v2h b, float c) {
#if __has_builtin(__builtin_amdgcn_fdot2)
    return __builtin_amdgcn_fdot2(a, b, c, false);
#else
    return c + (float)a.x * (float)b.x + (float)a.y * (float)b.y;
#endif
}

__device__ __forceinline__ v2h relu2(v2h a) {
    v2h z = {(_Float16)0.f, (_Float16)0.f};
#if __has_builtin(__builtin_elementwise_max)
    return __builtin_elementwise_max(a, z);
#else
    v2h r;
    r.x = a.x > (_Float16)0.f ? a.x : (_Float16)0.f;
    r.y = a.y > (_Float16)0.f ? a.y : (_Float16)0.f;
    return r;
#endif
}

// ---- prep: v[t] = dot(W2 row t, w3[0:128]); emit f16 copies of v and w3[128:]
__global__ void prep_v_kernel(const float* __restrict__ w2,
                              const float* __restrict__ w3,
                              _Float16* __restrict__ vh,      // 256 halves
                              _Float16* __restrict__ w3bh,    // 128 halves
                              float* __restrict__ vf) {       // 256 f32 (fallback)
    int t = threadIdx.x;  // 256 threads
    const float4* row = (const float4*)(w2 + (size_t)t * DDIM);
    const float4* w3c = (const float4*)w3;
    float acc = 0.f;
#pragma unroll
    for (int c = 0; c < DDIM / 4; ++c) {
        float4 a = row[c];
        float4 b = w3c[c];
        acc += a.x * b.x + a.y * b.y + a.z * b.z + a.w * b.w;
    }
    vf[t] = acc;
    vh[t] = (_Float16)acc;
    if (t < DDIM) w3bh[t] = (_Float16)w3[DDIM + t];
}

// ---- convert z (f32) -> zh (f16), 4 elems/thread
__global__ void cvt_z_kernel(const float* __restrict__ z,
                             _Float16* __restrict__ zh, int n4) {
    int i = blockIdx.x * blockDim.x + threadIdx.x;
    int stride = gridDim.x * blockDim.x;
    for (; i < n4; i += stride) {
        float4 a = ((const float4*)z)[i];
        v2h lo = {(_Float16)a.x, (_Float16)a.y};
        v2h hi = {(_Float16)a.z, (_Float16)a.w};
        float2 packed = {__builtin_bit_cast(float, lo), __builtin_bit_cast(float, hi)};
        ((float2*)zh)[i] = packed;
    }
}

// ---- main: 16 lanes per edge, 8 dims (one float4 of halves) per lane
__global__ void edge_score_f16_kernel(const int* __restrict__ e_true,
                                      const int* __restrict__ e_false,
                                      const _Float16* __restrict__ zh,
                                      const _Float16* __restrict__ vh,
                                      const _Float16* __restrict__ w3bh,
                                      float* __restrict__ out,
                                      int n_true, int n_total) {
    const int gtid    = blockIdx.x * blockDim.x + threadIdx.x;
    const int sub     = threadIdx.x & 15;
    const int group   = gtid >> 4;
    const int ngroups = (gridDim.x * blockDim.x) >> 4;

    // Per-lane invariant fragments: dims [8*sub, 8*sub+8)
    v2h vi[4], vj[4], wb[4];
#pragma unroll
    for (int k = 0; k < 4; ++k) {
        vi[k] = ((const v2h*)vh)[sub * 4 + k];
        vj[k] = ((const v2h*)vh)[64 + sub * 4 + k];
        wb[k] = ((const v2h*)w3bh)[sub * 4 + k];
    }

    for (int e = group; e < n_total; e += ngroups) {
        int2 ep = (e < n_true) ? ((const int2*)e_true)[e]
                               : ((const int2*)e_false)[e - n_true];

        float4 ri = ((const float4*)(zh + (size_t)ep.x * DDIM))[sub];
        float4 rj = ((const float4*)(zh + (size_t)ep.y * DDIM))[sub];
        v2h zi[4], zj[4];
        zi[0] = __builtin_bit_cast(v2h, ri.x); zi[1] = __builtin_bit_cast(v2h, ri.y);
        zi[2] = __builtin_bit_cast(v2h, ri.z); zi[3] = __builtin_bit_cast(v2h, ri.w);
        zj[0] = __builtin_bit_cast(v2h, rj.x); zj[1] = __builtin_bit_cast(v2h, rj.y);
        zj[2] = __builtin_bit_cast(v2h, rj.z); zj[3] = __builtin_bit_cast(v2h, rj.w);

        float p = 0.f;
#pragma unroll
        for (int k = 0; k < 4; ++k) {
            p = dot2acc(relu2(zi[k]), vi[k], p);
            p = dot2acc(relu2(zj[k]), vj[k], p);
            p = dot2acc(zi[k] * zj[k], wb[k], p);
        }

        // Reduce across the 16-lane group.
#pragma unroll
        for (int off = 8; off; off >>= 1) p += __shfl_down(p, off, 16);

        if (sub == 0) out[e] = 1.f / (1.f + __expf(-p));
    }
}

// ---- fallback f32 path (used only if d_ws is too small for the f16 table)
__global__ void edge_score_kernel(const int* __restrict__ e_true,
                                  const int* __restrict__ e_false,
                                  const float* __restrict__ z,
                                  const float* __restrict__ w3,
                                  const float* __restrict__ v,
                                  float* __restrict__ out,
                                  int n_true, int n_total) {
    const int gtid    = blockIdx.x * blockDim.x + threadIdx.x;
    const int sub     = threadIdx.x & 31;
    const int group   = gtid >> 5;
    const int ngroups = (gridDim.x * blockDim.x) >> 5;

    const float4 v1 = ((const float4*)v)[sub];
    const float4 v2 = ((const float4*)v)[32 + sub];
    const float4 wbv = ((const float4*)(w3 + DDIM))[sub];

    for (int e = group; e < n_total; e += ngroups) {
        int2 ep = (e < n_true) ? ((const int2*)e_true)[e]
                               : ((const int2*)e_false)[e - n_true];
        const float4 zi = ((const float4*)(z + (size_t)ep.x * DDIM))[sub];
        const float4 zj = ((const float4*)(z + (size_t)ep.y * DDIM))[sub];
        float p = fmaxf(zi.x, 0.f) * v1.x + fmaxf(zi.y, 0.f) * v1.y +
                  fmaxf(zi.z, 0.f) * v1.z + fmaxf(zi.w, 0.f) * v1.w +
                  fmaxf(zj.x, 0.f) * v2.x + fmaxf(zj.y, 0.f) * v2.y +
                  fmaxf(zj.z, 0.f) * v2.z + fmaxf(zj.w, 0.f) * v2.w +
                  zi.x * zj.x * wbv.x + zi.y * zj.y * wbv.y +
                  zi.z * zj.z * wbv.z + zi.w * zj.w * wbv.w;
#pragma unroll
        for (int off = 16; off; off >>= 1) p += __shfl_down(p, off, 32);
        if (sub == 0) out[e] = 1.f / (1.f + __expf(-p));
    }
}

extern "C" void kernel_launch(void* const* d_in, const int* in_sizes, int n_in,
                              void* d_out, int out_size, void* d_ws, size_t ws_size,
                              hipStream_t stream) {
    // inputs: 0=X(unused), 1=train_edges, 2=train_false_edges, 3=z, 4=W2, 5=w3
    const int*   e_true  = (const int*)d_in[1];
    const int*   e_false = (const int*)d_in[2];
    const float* z       = (const float*)d_in[3];
    const float* w2      = (const float*)d_in[4];
    const float* w3      = (const float*)d_in[5];
    float*       out     = (float*)d_out;

    const int n_true  = in_sizes[1] / 2;
    const int n_total = out_size;
    const int z_elems = in_sizes[3];          // NODE_SIZE * 128

    // ws layout: [0,512) vh, [512,768) w3bh, [768,1792) vf, [2048, 2048+2*z_elems) zh
    _Float16* vh   = (_Float16*)d_ws;
    _Float16* w3bh = (_Float16*)((char*)d_ws + 512);
    float*    vf   = (float*)((char*)d_ws + 768);
    _Float16* zh   = (_Float16*)((char*)d_ws + 2048);

    const size_t need = 2048 + (size_t)z_elems * 2;

    prep_v_kernel<<<1, 256, 0, stream>>>(w2, w3, vh, w3bh, vf);

    if (ws_size >= need) {
        cvt_z_kernel<<<2048, 256, 0, stream>>>(z, zh, z_elems / 4);
        edge_score_f16_kernel<<<4096, 256, 0, stream>>>(e_true, e_false, zh, vh,
                                                        w3bh, out, n_true, n_total);
    } else {
        edge_score_kernel<<<4096, 256, 0, stream>>>(e_true, e_false, z, w3, vf,
                                                    out, n_true, n_total);
    }
}